// Round 7
// baseline (192.155 us; speedup 1.0000x reference)
//
#include <hip/hip_runtime.h>
#include <math.h>

// Attention_5471788335537 on gfx950: b=8, dim=256, 32x32, heads=8, dhead=64.
// Round 7: (1) zero-padded xt [b][34*34][256] — 3x3 shift becomes a
// wave-uniform scalar offset (deletes per-lane bounds check + cndmask from
// the kv K-loop); (2) q-GEMM fused into the kv dispatch as mt>=8 blocks
// (center-shift K-slice, 4 kts); (3) transpose_x writes padded layout half8.
#define BATCH 8
#define DIM   256
#define NPIX  1024
#define DHEAD 64
#define INNER 512
#define KVCH  1024
#define PPIX  1156   // 34*34 padded pixels

typedef _Float16 half8 __attribute__((ext_vector_type(8)));
typedef _Float16 half4 __attribute__((ext_vector_type(4)));
typedef float    f32x4 __attribute__((ext_vector_type(4)));
#define MFMA16(a, b, c) __builtin_amdgcn_mfma_f32_16x16x32_f16(a, b, c, 0, 0, 0)

static __device__ __forceinline__ float gelu_f(float v) {
    return 0.5f * v * (1.0f + erff(v * 0.70710678118654752440f));
}

static __device__ __forceinline__ void gload16(const _Float16* g, _Float16* l) {
    __builtin_amdgcn_global_load_lds(
        (const __attribute__((address_space(1))) unsigned int*)g,
        (__attribute__((address_space(3))) unsigned int*)l, 16, 0, 0);
}

// ---------------------------------------------------------------------------
// prep: weights -> f16 (Wkv reordered [oc][ic][9] -> [oc][s*256+ic])
// ---------------------------------------------------------------------------
__global__ __launch_bounds__(256) void prep_w_kernel(
    const float* __restrict__ Wq, const float* __restrict__ Wkv,
    const float* __restrict__ Wout, _Float16* __restrict__ Aq,
    _Float16* __restrict__ Akv, _Float16* __restrict__ Aout)
{
    const int e = blockIdx.x * 256 + threadIdx.x;
    if (e < 131072) Aq[e] = (_Float16)Wq[e];
    const int e2 = e - 131072;
    if (e2 >= 0 && e2 < 2359296) {
        int oc = e2 / 2304, r = e2 - oc * 2304;
        int s = r >> 8, ic = r & 255;
        Akv[e2] = (_Float16)Wkv[oc * 2304 + ic * 9 + s];
    }
    const int e3 = e - 131072 - 2359296;
    if (e3 >= 0 && e3 < 131072) Aout[e3] = (_Float16)Wout[e3];
}

// ---------------------------------------------------------------------------
// prep: x [b][256][1024] f32 -> xtp [b][34*34 padded][256] f16 (interior only;
// halo pre-zeroed by memset). half8 stores.
// grid (16 pixtiles of 64, 4 ictiles, 8)
// ---------------------------------------------------------------------------
__global__ __launch_bounds__(256) void transpose_x_kernel(
    const float* __restrict__ x, _Float16* __restrict__ xtp)
{
    __shared__ float ts[64][65];
    const int pt = blockIdx.x * 64, ic0 = blockIdx.y * 64, b = blockIdx.z;
    const int tid = threadIdx.x;
    const float* xb = x + (((size_t)(b * DIM + ic0)) << 10) + pt;
#pragma unroll
    for (int e = tid; e < 4096; e += 256) {
        int i = e >> 6, p = e & 63;
        ts[i][p] = xb[((size_t)i << 10) + p];
    }
    __syncthreads();
#pragma unroll
    for (int e = tid; e < 512; e += 256) {
        int p = e >> 3, ig = e & 7;
        int gp = pt + p, y = gp >> 5, xc = gp & 31;
        half8 v;
#pragma unroll
        for (int u = 0; u < 8; ++u) v[u] = (_Float16)ts[ig * 8 + u][p];
        *(half8*)&xtp[((size_t)b * PPIX + (y + 1) * 34 + xc + 1) * 256 + ic0 + ig * 8] = v;
    }
}

// ---------------------------------------------------------------------------
// Fused q + kv implicit GEMM over padded xtp. grid (8 pixtiles, 12, 8).
// mt<8: A=Akv (K=2304, 36 kts, shift s=kt>>2, scalar offset doff*256);
//       epilogue K->ktp headwise, V->vb channel-major.
// mt>=8: A=Aq (K=256, 4 kts, center shift), epilogue q*0.125 -> qt headwise.
// Staging XOR swizzle as round 5 (key=row&7 via scol).
// ---------------------------------------------------------------------------
__global__ __launch_bounds__(256) void qkv_gemm_kernel(
    const _Float16* __restrict__ Akv, const _Float16* __restrict__ Aq,
    const _Float16* __restrict__ xtp, _Float16* __restrict__ qt,
    _Float16* __restrict__ ktp, _Float16* __restrict__ vb)
{
    __shared__ _Float16 As[128 * 64];
    __shared__ _Float16 Bs[128 * 64];
    const int nt = blockIdx.x, mt = blockIdx.y, b = blockIdx.z;
    const bool QBLK = (mt >= 8);
    const int tid = threadIdx.x;
    const int w = tid >> 6, lane = tid & 63;
    const int quad = lane >> 4, l15 = lane & 15;
    const int m0 = (QBLK ? mt - 8 : mt) * 128, p0 = nt * 128;
    const int wm = (w >> 1) * 64, wn = (w & 1) * 64;
    const f32x4 Z4 = {0.f, 0.f, 0.f, 0.f};

    const int srow = lane >> 3;                    // row within 8-row chunk
    const int scol = ((lane & 7) ^ srow) * 8;      // swizzled k offset (key=row&7)

    const _Float16* abase = QBLK ? Aq : Akv;
    const int astride = QBLK ? 256 : 2304;
    const int ktend = QBLK ? 4 : 36;

    const _Float16* agp[4];
    const _Float16* bgp[4];
#pragma unroll
    for (int c = 0; c < 4; ++c) {
        int row = (w * 4 + c) * 8 + srow;
        agp[c] = abase + (size_t)(m0 + row) * astride + scol;
        int p = p0 + row, py = p >> 5, px = p & 31;
        bgp[c] = xtp + ((size_t)b * PPIX + (py + 1) * 34 + px + 1) * 256 + scol;
    }

    f32x4 acc[4][4];
#pragma unroll
    for (int mi = 0; mi < 4; ++mi)
#pragma unroll
        for (int ni = 0; ni < 4; ++ni) acc[mi][ni] = Z4;

    for (int kt = 0; kt < ktend; ++kt) {
        __syncthreads();
        const int s = QBLK ? 4 : (kt >> 2);
        const int doff = (s / 3 - 1) * 34 + (s - (s / 3) * 3) - 1;   // dy*34+dx
        const int boff = doff * 256 + (kt & 3) * 64;                 // wave-uniform
#pragma unroll
        for (int c = 0; c < 4; ++c)
            gload16(agp[c] + kt * 64, &As[(w * 4 + c) * 512]);
#pragma unroll
        for (int c = 0; c < 4; ++c)
            gload16(bgp[c] + boff, &Bs[(w * 4 + c) * 512]);
        __syncthreads();
#pragma unroll
        for (int ks = 0; ks < 2; ++ks) {
            half8 av[4], bv[4];
#pragma unroll
            for (int mi = 0; mi < 4; ++mi) {
                const int r = wm + mi * 16 + l15;
                av[mi] = *(const half8*)&As[r * 64 + (((ks * 4 + quad) ^ (l15 & 7)) << 3)];
            }
#pragma unroll
            for (int ni = 0; ni < 4; ++ni) {
                const int r = wn + ni * 16 + l15;
                bv[ni] = *(const half8*)&Bs[r * 64 + (((ks * 4 + quad) ^ (l15 & 7)) << 3)];
            }
#pragma unroll
            for (int mi = 0; mi < 4; ++mi)
#pragma unroll
                for (int ni = 0; ni < 4; ++ni)
                    acc[mi][ni] = MFMA16(av[mi], bv[ni], acc[mi][ni]);
        }
    }

#pragma unroll
    for (int mi = 0; mi < 4; ++mi) {
        const int mbase = m0 + wm + mi * 16;   // multiple of 16
        if (!QBLK && mbase >= 512) {
            // V: f16 channel-major [(b*512 + m-512)<<10 + pix]
#pragma unroll
            for (int r = 0; r < 4; ++r) {
                const int mv = mbase + quad * 4 + r - 512;
#pragma unroll
                for (int ni = 0; ni < 4; ++ni) {
                    const int pix = p0 + wn + ni * 16 + l15;
                    vb[(((size_t)(b * 512 + mv)) << 10) + pix] = (_Float16)acc[mi][ni][r];
                }
            }
        } else {
            // headwise: [(b*8+h)<<10 + pix][64], d contiguous via quad*4+r
            const int h  = mbase >> 6;
            const int dd = (mbase & 63) + quad * 4;
            _Float16* dst = QBLK ? qt : ktp;
#pragma unroll
            for (int ni = 0; ni < 4; ++ni) {
                const int pix = p0 + wn + ni * 16 + l15;
                half4 v4;
#pragma unroll
                for (int r = 0; r < 4; ++r) {
                    float vv = acc[mi][ni][r];
                    if (QBLK) vv *= 0.125f;   // fold attention scale into q
                    v4[r] = (_Float16)vv;
                }
                *(half4*)&dst[((((size_t)(b * 8 + h)) << 10) + pix) * 64 + dd] = v4;
            }
        }
    }
}

// ---------------------------------------------------------------------------
// GEMM (m97 structure + swizzle) for the output projection. EPI=1: f32+bias.
// ---------------------------------------------------------------------------
template<int M, int K, int KROW>
__global__ __launch_bounds__(256) void out_gemm_kernel(
    const _Float16* __restrict__ A, const _Float16* __restrict__ act,
    float* __restrict__ Cout, const float* __restrict__ bias)
{
    __shared__ _Float16 As[128 * 64];
    __shared__ _Float16 Bs[128 * 64];
    const int nt = blockIdx.x, mt = blockIdx.y, b = blockIdx.z;
    const int tid = threadIdx.x;
    const int w = tid >> 6, lane = tid & 63;
    const int quad = lane >> 4, l15 = lane & 15;
    const int m0 = mt * 128, p0 = nt * 128;
    const int wm = (w >> 1) * 64, wn = (w & 1) * 64;
    const f32x4 Z4 = {0.f, 0.f, 0.f, 0.f};

    const int srow = lane >> 3;
    const int scol = ((lane & 7) ^ srow) * 8;

    int prow[4];
    const _Float16* agp[4];
#pragma unroll
    for (int c = 0; c < 4; ++c) {
        int row = (w * 4 + c) * 8 + srow;
        prow[c] = row;
        agp[c] = A + (size_t)(m0 + row) * K + scol;
    }

    f32x4 acc[4][4];
#pragma unroll
    for (int mi = 0; mi < 4; ++mi)
#pragma unroll
        for (int ni = 0; ni < 4; ++ni) acc[mi][ni] = Z4;

    for (int kt = 0; kt < K / 64; ++kt) {
        __syncthreads();
#pragma unroll
        for (int c = 0; c < 4; ++c)
            gload16(agp[c] + kt * 64, &As[(w * 4 + c) * 512]);
#pragma unroll
        for (int c = 0; c < 4; ++c)
            gload16(act + (size_t)(b * NPIX + p0 + prow[c]) * KROW + kt * 64 + scol,
                    &Bs[(w * 4 + c) * 512]);
        __syncthreads();
#pragma unroll
        for (int ks = 0; ks < 2; ++ks) {
            half8 av[4], bv[4];
#pragma unroll
            for (int mi = 0; mi < 4; ++mi) {
                const int r = wm + mi * 16 + l15;
                av[mi] = *(const half8*)&As[r * 64 + (((ks * 4 + quad) ^ (l15 & 7)) << 3)];
            }
#pragma unroll
            for (int ni = 0; ni < 4; ++ni) {
                const int r = wn + ni * 16 + l15;
                bv[ni] = *(const half8*)&Bs[r * 64 + (((ks * 4 + quad) ^ (l15 & 7)) << 3)];
            }
#pragma unroll
            for (int mi = 0; mi < 4; ++mi)
#pragma unroll
                for (int ni = 0; ni < 4; ++ni)
                    acc[mi][ni] = MFMA16(av[mi], bv[ni], acc[mi][ni]);
        }
    }

#pragma unroll
    for (int mi = 0; mi < 4; ++mi) {
#pragma unroll
        for (int r = 0; r < 4; ++r) {
            const int m = m0 + wm + mi * 16 + quad * 4 + r;
            const float bv = bias[m];
#pragma unroll
            for (int ni = 0; ni < 4; ++ni) {
                const int pix = p0 + wn + ni * 16 + l15;
                Cout[(((size_t)(b * M + m)) << 10) + pix] = acc[mi][ni][r] + bv;
            }
        }
    }
}

// ---------------------------------------------------------------------------
// Attention (round-6 structure: native exp, ones-MFMA row sums, S^T layout).
// ---------------------------------------------------------------------------
__global__ __launch_bounds__(256) void attn_kernel(
    const _Float16* __restrict__ qt,   // [(b*8+h)<<10 + pix]*64 + d, pre-scaled
    const _Float16* __restrict__ ktp,  // (bh<<16) + pix*64 + d
    const _Float16* __restrict__ vbb,  // [(b*512 + h*64 + d)<<10] + pix
    _Float16* __restrict__ gout)       // [b*1024+pix][512]
{
    __shared__ _Float16 Ks[128 * 64];   // [j][d], chunks xor (j&7)
    __shared__ _Float16 Vs[64 * 128];   // [d][j], chunks xor (d&15)
    __shared__ _Float16 Pb[128 * 128];  // [i][j], chunks xor (i&15); wave-private
    const int qtile = blockIdx.x, bh = blockIdx.y;
    const int b = bh >> 3, h = bh & 7;
    const int p0 = qtile * 128;
    const int tid = threadIdx.x;
    const int w = tid >> 6, lane = tid & 63;
    const int quad = lane >> 4, l15 = lane & 15;
    const f32x4 Z4 = {0.f, 0.f, 0.f, 0.f};

    half8 ones;
#pragma unroll
    for (int u = 0; u < 8; ++u) ones[u] = (_Float16)1.0f;

    half8 qf[2][2];
    {
        const _Float16* qrow =
            qt + ((((size_t)(bh)) << 10) + p0 + w * 32 + l15) * 64;
#pragma unroll
        for (int iff = 0; iff < 2; ++iff)
#pragma unroll
            for (int ks = 0; ks < 2; ++ks)
                qf[iff][ks] = *(const half8*)(qrow + iff * 16 * 64 + ks * 32 + quad * 8);
    }

    const _Float16* kbase = ktp + ((size_t)bh << 16);
    const _Float16* vbase = vbb + (((size_t)(b * 512 + h * 64)) << 10);

    f32x4 oacc[4][2];
#pragma unroll
    for (int mf = 0; mf < 4; ++mf)
#pragma unroll
        for (int iff = 0; iff < 2; ++iff) oacc[mf][iff] = Z4;
    f32x4 racc[2] = {Z4, Z4};

    const int kchunk = (lane & 7) ^ (lane >> 3);
    for (int kt = 0; kt < 8; ++kt) {
        const int pk = kt * 128;
        __syncthreads();
        const _Float16* kg = kbase + (size_t)pk * 64;
#pragma unroll
        for (int i = 0; i < 4; ++i) {
            const int t = i * 4 + w;
            gload16(kg + (t * 8 + (lane >> 3)) * 64 + kchunk * 8, &Ks[t * 512]);
        }
#pragma unroll
        for (int i = 0; i < 4; ++i) {
            const int t = i * 4 + w;
            const int vd = t * 4 + (lane >> 4);
            gload16(vbase + ((size_t)vd << 10) + pk + (((lane & 15) ^ (vd & 15)) << 3),
                    &Vs[t * 512]);
        }
        __syncthreads();

#pragma unroll
        for (int g = 0; g < 2; ++g) {
            f32x4 s[4][2];
#pragma unroll
            for (int jf2 = 0; jf2 < 4; ++jf2) {
                const int jr = (g * 4 + jf2) * 16 + l15;
                const half8 ka0 = *(const half8*)&Ks[jr * 64 + ((quad ^ (l15 & 7)) << 3)];
                const half8 ka1 = *(const half8*)&Ks[jr * 64 + (((4 + quad) ^ (l15 & 7)) << 3)];
#pragma unroll
                for (int iff = 0; iff < 2; ++iff) {
                    s[jf2][iff] = MFMA16(ka0, qf[iff][0], Z4);
                    s[jf2][iff] = MFMA16(ka1, qf[iff][1], s[jf2][iff]);
                }
            }
#pragma unroll
            for (int jf2 = 0; jf2 < 4; ++jf2) {
#pragma unroll
                for (int iff = 0; iff < 2; ++iff) {
                    half4 pv4;
#pragma unroll
                    for (int r = 0; r < 4; ++r)
                        pv4[r] = (_Float16)__expf(s[jf2][iff][r] - 8.0f);
                    const int i = w * 32 + iff * 16 + l15;
                    const int c = ((g * 4 + jf2) << 1) + (quad >> 1);
                    *(half4*)&Pb[i * 128 + ((c ^ l15) << 3) + ((quad & 1) << 2)] = pv4;
                }
            }
        }
#pragma unroll
        for (int kc = 0; kc < 4; ++kc) {
            half8 bv[2];
#pragma unroll
            for (int iff = 0; iff < 2; ++iff) {
                const int i = w * 32 + iff * 16 + l15;
                bv[iff] = *(const half8*)&Pb[i * 128 + (((kc * 4 + quad) ^ l15) << 3)];
                racc[iff] = MFMA16(ones, bv[iff], racc[iff]);
            }
#pragma unroll
            for (int mf = 0; mf < 4; ++mf) {
                const int vr = mf * 16 + l15;
                const half8 va = *(const half8*)&Vs[vr * 128 + (((kc * 4 + quad) ^ l15) << 3)];
#pragma unroll
                for (int iff = 0; iff < 2; ++iff)
                    oacc[mf][iff] = MFMA16(va, bv[iff], oacc[mf][iff]);
            }
        }
    }

    float rinv[2];
#pragma unroll
    for (int iff = 0; iff < 2; ++iff) rinv[iff] = 1.f / racc[iff][0];

    __syncthreads();
    _Float16* scr = Pb;  // [128 rows][72 halves]
#pragma unroll
    for (int mf = 0; mf < 4; ++mf) {
#pragma unroll
        for (int iff = 0; iff < 2; ++iff) {
            half4 o4;
#pragma unroll
            for (int r = 0; r < 4; ++r)
                o4[r] = (_Float16)gelu_f(oacc[mf][iff][r] * rinv[iff]);
            const int i = w * 32 + iff * 16 + l15;
            *(half4*)&scr[i * 72 + mf * 16 + quad * 4] = o4;
        }
    }
    __syncthreads();
    _Float16* go = gout + ((size_t)(b * NPIX + p0)) * INNER + h * 64;
#pragma unroll
    for (int it = 0; it < 4; ++it) {
        const int e = tid + it * 256;
        const int p = e >> 3, dg = e & 7;
        *(half8*)(go + (size_t)p * INNER + dg * 8) = *(const half8*)&scr[p * 72 + dg * 8];
    }
}

// ---------------------------------------------------------------------------
// Workspace (f16 units, ~43.5 MB):
//   xtp 2.37M | Aq 128K | Akv 2.25M | Aout 128K | qt 4M | vb 4M | ktp 4M | gout 4M
// ---------------------------------------------------------------------------
extern "C" void kernel_launch(void* const* d_in, const int* in_sizes, int n_in,
                              void* d_out, int out_size, void* d_ws, size_t ws_size,
                              hipStream_t stream)
{
    const float* x    = (const float*)d_in[0];
    const float* Wq   = (const float*)d_in[1];
    const float* Wkv  = (const float*)d_in[2];
    const float* Wout = (const float*)d_in[3];
    const float* bout = (const float*)d_in[4];
    float* out = (float*)d_out;

    _Float16* xtp  = (_Float16*)d_ws;
    _Float16* Aq   = xtp  + (size_t)BATCH * PPIX * DIM;
    _Float16* Akv  = Aq   + (size_t)INNER * DIM;
    _Float16* Aout = Akv  + (size_t)KVCH * 2304;
    _Float16* qt   = Aout + (size_t)DIM * INNER;
    _Float16* vb   = qt   + (size_t)BATCH * NPIX * INNER;
    _Float16* ktp  = vb   + (size_t)BATCH * NPIX * INNER;
    _Float16* gout = ktp  + (size_t)BATCH * NPIX * INNER;

    // zero the padded-x halo (interior overwritten by transpose_x)
    (void)hipMemsetAsync(xtp, 0, (size_t)BATCH * PPIX * DIM * sizeof(_Float16), stream);

    prep_w_kernel<<<10240, 256, 0, stream>>>(Wq, Wkv, Wout, Aq, Akv, Aout);
    transpose_x_kernel<<<dim3(16, 4, BATCH), 256, 0, stream>>>(x, xtp);
    qkv_gemm_kernel<<<dim3(8, 12, BATCH), 256, 0, stream>>>(Akv, Aq, xtp, qt, ktp, vb);
    attn_kernel<<<dim3(8, 64), 256, 0, stream>>>(qt, ktp, vb, gout);
    out_gemm_kernel<DIM, 512, 512>
        <<<dim3(8, 2, BATCH), 256, 0, stream>>>(Aout, gout, out, bout);
}

// Round 8
// 190.243 us; speedup vs baseline: 1.0100x; 1.0100x over previous
//
#include <hip/hip_runtime.h>
#include <math.h>

// Attention_5471788335537 on gfx950: b=8, dim=256, 32x32, heads=8, dhead=64.
// Round 8: GEMM tiles 128Mx64N (was 128x128) -> fused qkv grid 1536 blocks
// (~6/CU vs 2/CU): the m97 2-barrier K-loop is latency-bound at 2 blocks/CU
// (r7: MfmaUtil 24%, Occ 15.5%); more co-resident blocks cover the vmcnt
// drains. out_gemm likewise 256 blocks (was 128 = half the CUs idle).
#define BATCH 8
#define DIM   256
#define NPIX  1024
#define DHEAD 64
#define INNER 512
#define KVCH  1024
#define PPIX  1156   // 34*34 padded pixels

typedef _Float16 half8 __attribute__((ext_vector_type(8)));
typedef _Float16 half4 __attribute__((ext_vector_type(4)));
typedef float    f32x4 __attribute__((ext_vector_type(4)));
#define MFMA16(a, b, c) __builtin_amdgcn_mfma_f32_16x16x32_f16(a, b, c, 0, 0, 0)

static __device__ __forceinline__ float gelu_f(float v) {
    return 0.5f * v * (1.0f + erff(v * 0.70710678118654752440f));
}

static __device__ __forceinline__ void gload16(const _Float16* g, _Float16* l) {
    __builtin_amdgcn_global_load_lds(
        (const __attribute__((address_space(1))) unsigned int*)g,
        (__attribute__((address_space(3))) unsigned int*)l, 16, 0, 0);
}

// ---------------------------------------------------------------------------
// prep: weights -> f16 (Wkv reordered [oc][ic][9] -> [oc][s*256+ic])
// ---------------------------------------------------------------------------
__global__ __launch_bounds__(256) void prep_w_kernel(
    const float* __restrict__ Wq, const float* __restrict__ Wkv,
    const float* __restrict__ Wout, _Float16* __restrict__ Aq,
    _Float16* __restrict__ Akv, _Float16* __restrict__ Aout)
{
    const int e = blockIdx.x * 256 + threadIdx.x;
    if (e < 131072) Aq[e] = (_Float16)Wq[e];
    const int e2 = e - 131072;
    if (e2 >= 0 && e2 < 2359296) {
        int oc = e2 / 2304, r = e2 - oc * 2304;
        int s = r >> 8, ic = r & 255;
        Akv[e2] = (_Float16)Wkv[oc * 2304 + ic * 9 + s];
    }
    const int e3 = e - 131072 - 2359296;
    if (e3 >= 0 && e3 < 131072) Aout[e3] = (_Float16)Wout[e3];
}

// ---------------------------------------------------------------------------
// prep: x [b][256][1024] f32 -> xtp [b][34*34 padded][256] f16 (interior only;
// halo pre-zeroed by memset). half8 stores.
// ---------------------------------------------------------------------------
__global__ __launch_bounds__(256) void transpose_x_kernel(
    const float* __restrict__ x, _Float16* __restrict__ xtp)
{
    __shared__ float ts[64][65];
    const int pt = blockIdx.x * 64, ic0 = blockIdx.y * 64, b = blockIdx.z;
    const int tid = threadIdx.x;
    const float* xb = x + (((size_t)(b * DIM + ic0)) << 10) + pt;
#pragma unroll
    for (int e = tid; e < 4096; e += 256) {
        int i = e >> 6, p = e & 63;
        ts[i][p] = xb[((size_t)i << 10) + p];
    }
    __syncthreads();
#pragma unroll
    for (int e = tid; e < 512; e += 256) {
        int p = e >> 3, ig = e & 7;
        int gp = pt + p, y = gp >> 5, xc = gp & 31;
        half8 v;
#pragma unroll
        for (int u = 0; u < 8; ++u) v[u] = (_Float16)ts[ig * 8 + u][p];
        *(half8*)&xtp[((size_t)b * PPIX + (y + 1) * 34 + xc + 1) * 256 + ic0 + ig * 8] = v;
    }
}

// ---------------------------------------------------------------------------
// Fused q + kv implicit GEMM, tile 128M x 64N. grid (16 pixtiles, 12, 8).
// 4 waves, wave w owns M rows w*32..+31 (2 i-frags) x full 64 N.
// mt<8: A=Akv (K=2304, 36 kts, shift via wave-uniform padded offset);
//       mt<4 -> K headwise to ktp; mt 4..7 -> V channel-major to vb.
// mt>=8: A=Aq (K=256, 4 kts, center shift), q*0.125 -> qt headwise.
// XOR-chunk staging swizzle throughout (key = row&7).
// ---------------------------------------------------------------------------
__global__ __launch_bounds__(256) void qkv_gemm_kernel(
    const _Float16* __restrict__ Akv, const _Float16* __restrict__ Aq,
    const _Float16* __restrict__ xtp, _Float16* __restrict__ qt,
    _Float16* __restrict__ ktp, _Float16* __restrict__ vb)
{
    __shared__ _Float16 As[128 * 64];   // 16 KB
    __shared__ _Float16 Bs[64 * 64];    // 8 KB
    const int nt = blockIdx.x, mt = blockIdx.y, b = blockIdx.z;
    const bool QBLK = (mt >= 8);
    const int tid = threadIdx.x;
    const int w = tid >> 6, lane = tid & 63;
    const int quad = lane >> 4, l15 = lane & 15;
    const int m0 = (QBLK ? mt - 8 : mt) * 128, p0 = nt * 64;
    const int wm = w * 32;
    const f32x4 Z4 = {0.f, 0.f, 0.f, 0.f};

    const int srow = lane >> 3;
    const int scol = ((lane & 7) ^ srow) * 8;

    const _Float16* abase = QBLK ? Aq : Akv;
    const int astride = QBLK ? 256 : 2304;
    const int ktend = QBLK ? 4 : 36;

    const _Float16* agp[4];
#pragma unroll
    for (int c = 0; c < 4; ++c) {
        int row = (w * 4 + c) * 8 + srow;
        agp[c] = abase + (size_t)(m0 + row) * astride + scol;
    }
    const _Float16* bgp[2];
#pragma unroll
    for (int c = 0; c < 2; ++c) {
        int row = (w * 2 + c) * 8 + srow;
        int p = p0 + row, py = p >> 5, px = p & 31;
        bgp[c] = xtp + ((size_t)b * PPIX + (py + 1) * 34 + px + 1) * 256 + scol;
    }

    f32x4 acc[2][4];
#pragma unroll
    for (int mi = 0; mi < 2; ++mi)
#pragma unroll
        for (int ni = 0; ni < 4; ++ni) acc[mi][ni] = Z4;

    for (int kt = 0; kt < ktend; ++kt) {
        __syncthreads();
        const int s = QBLK ? 4 : (kt >> 2);
        const int doff = (s / 3 - 1) * 34 + (s - (s / 3) * 3) - 1;   // dy*34+dx
        const int boff = doff * 256 + (kt & 3) * 64;                 // wave-uniform
#pragma unroll
        for (int c = 0; c < 4; ++c)
            gload16(agp[c] + kt * 64, &As[(w * 4 + c) * 512]);
#pragma unroll
        for (int c = 0; c < 2; ++c)
            gload16(bgp[c] + boff, &Bs[(w * 2 + c) * 512]);
        __syncthreads();
#pragma unroll
        for (int ks = 0; ks < 2; ++ks) {
            half8 av[2], bv[4];
#pragma unroll
            for (int mi = 0; mi < 2; ++mi) {
                const int r = wm + mi * 16 + l15;
                av[mi] = *(const half8*)&As[r * 64 + (((ks * 4 + quad) ^ (l15 & 7)) << 3)];
            }
#pragma unroll
            for (int ni = 0; ni < 4; ++ni) {
                const int r = ni * 16 + l15;
                bv[ni] = *(const half8*)&Bs[r * 64 + (((ks * 4 + quad) ^ (l15 & 7)) << 3)];
            }
#pragma unroll
            for (int mi = 0; mi < 2; ++mi)
#pragma unroll
                for (int ni = 0; ni < 4; ++ni)
                    acc[mi][ni] = MFMA16(av[mi], bv[ni], acc[mi][ni]);
        }
    }

#pragma unroll
    for (int mi = 0; mi < 2; ++mi) {
        const int mbase = m0 + wm + mi * 16;   // multiple of 16
        if (!QBLK && mbase >= 512) {
            // V: f16 channel-major [(b*512 + m-512)<<10 + pix]
#pragma unroll
            for (int r = 0; r < 4; ++r) {
                const int mv = mbase + quad * 4 + r - 512;
#pragma unroll
                for (int ni = 0; ni < 4; ++ni) {
                    const int pix = p0 + ni * 16 + l15;
                    vb[(((size_t)(b * 512 + mv)) << 10) + pix] = (_Float16)acc[mi][ni][r];
                }
            }
        } else {
            // headwise: [(b*8+h)<<10 + pix][64], d contiguous via quad*4+r
            const int h  = mbase >> 6;
            const int dd = (mbase & 63) + quad * 4;
            _Float16* dst = QBLK ? qt : ktp;
#pragma unroll
            for (int ni = 0; ni < 4; ++ni) {
                const int pix = p0 + ni * 16 + l15;
                half4 v4;
#pragma unroll
                for (int r = 0; r < 4; ++r) {
                    float vv = acc[mi][ni][r];
                    if (QBLK) vv *= 0.125f;   // fold attention scale into q
                    v4[r] = (_Float16)vv;
                }
                *(half4*)&dst[((((size_t)(b * 8 + h)) << 10) + pix) * 64 + dd] = v4;
            }
        }
    }
}

// ---------------------------------------------------------------------------
// Output projection GEMM, tile 128M x 64N. grid (16, 2, 8) = 256 blocks.
// ---------------------------------------------------------------------------
template<int M, int K, int KROW>
__global__ __launch_bounds__(256) void out_gemm_kernel(
    const _Float16* __restrict__ A, const _Float16* __restrict__ act,
    float* __restrict__ Cout, const float* __restrict__ bias)
{
    __shared__ _Float16 As[128 * 64];
    __shared__ _Float16 Bs[64 * 64];
    const int nt = blockIdx.x, mt = blockIdx.y, b = blockIdx.z;
    const int tid = threadIdx.x;
    const int w = tid >> 6, lane = tid & 63;
    const int quad = lane >> 4, l15 = lane & 15;
    const int m0 = mt * 128, p0 = nt * 64;
    const int wm = w * 32;
    const f32x4 Z4 = {0.f, 0.f, 0.f, 0.f};

    const int srow = lane >> 3;
    const int scol = ((lane & 7) ^ srow) * 8;

    const _Float16* agp[4];
#pragma unroll
    for (int c = 0; c < 4; ++c) {
        int row = (w * 4 + c) * 8 + srow;
        agp[c] = A + (size_t)(m0 + row) * K + scol;
    }
    const _Float16* bgp[2];
#pragma unroll
    for (int c = 0; c < 2; ++c) {
        int row = (w * 2 + c) * 8 + srow;
        bgp[c] = act + (size_t)(b * NPIX + p0 + row) * KROW + scol;
    }

    f32x4 acc[2][4];
#pragma unroll
    for (int mi = 0; mi < 2; ++mi)
#pragma unroll
        for (int ni = 0; ni < 4; ++ni) acc[mi][ni] = Z4;

    for (int kt = 0; kt < K / 64; ++kt) {
        __syncthreads();
#pragma unroll
        for (int c = 0; c < 4; ++c)
            gload16(agp[c] + kt * 64, &As[(w * 4 + c) * 512]);
#pragma unroll
        for (int c = 0; c < 2; ++c)
            gload16(bgp[c] + kt * 64, &Bs[(w * 2 + c) * 512]);
        __syncthreads();
#pragma unroll
        for (int ks = 0; ks < 2; ++ks) {
            half8 av[2], bv[4];
#pragma unroll
            for (int mi = 0; mi < 2; ++mi) {
                const int r = wm + mi * 16 + l15;
                av[mi] = *(const half8*)&As[r * 64 + (((ks * 4 + quad) ^ (l15 & 7)) << 3)];
            }
#pragma unroll
            for (int ni = 0; ni < 4; ++ni) {
                const int r = ni * 16 + l15;
                bv[ni] = *(const half8*)&Bs[r * 64 + (((ks * 4 + quad) ^ (l15 & 7)) << 3)];
            }
#pragma unroll
            for (int mi = 0; mi < 2; ++mi)
#pragma unroll
                for (int ni = 0; ni < 4; ++ni)
                    acc[mi][ni] = MFMA16(av[mi], bv[ni], acc[mi][ni]);
        }
    }

#pragma unroll
    for (int mi = 0; mi < 2; ++mi) {
#pragma unroll
        for (int r = 0; r < 4; ++r) {
            const int m = m0 + wm + mi * 16 + quad * 4 + r;
            const float bv = bias[m];
#pragma unroll
            for (int ni = 0; ni < 4; ++ni) {
                const int pix = p0 + ni * 16 + l15;
                Cout[(((size_t)(b * M + m)) << 10) + pix] = acc[mi][ni][r] + bv;
            }
        }
    }
}

// ---------------------------------------------------------------------------
// Attention (round-6 structure: native exp, ones-MFMA row sums, S^T layout).
// ---------------------------------------------------------------------------
__global__ __launch_bounds__(256) void attn_kernel(
    const _Float16* __restrict__ qt,   // [(b*8+h)<<10 + pix]*64 + d, pre-scaled
    const _Float16* __restrict__ ktp,  // (bh<<16) + pix*64 + d
    const _Float16* __restrict__ vbb,  // [(b*512 + h*64 + d)<<10] + pix
    _Float16* __restrict__ gout)       // [b*1024+pix][512]
{
    __shared__ _Float16 Ks[128 * 64];   // [j][d], chunks xor (j&7)
    __shared__ _Float16 Vs[64 * 128];   // [d][j], chunks xor (d&15)
    __shared__ _Float16 Pb[128 * 128];  // [i][j], chunks xor (i&15); wave-private
    const int qtile = blockIdx.x, bh = blockIdx.y;
    const int b = bh >> 3, h = bh & 7;
    const int p0 = qtile * 128;
    const int tid = threadIdx.x;
    const int w = tid >> 6, lane = tid & 63;
    const int quad = lane >> 4, l15 = lane & 15;
    const f32x4 Z4 = {0.f, 0.f, 0.f, 0.f};

    half8 ones;
#pragma unroll
    for (int u = 0; u < 8; ++u) ones[u] = (_Float16)1.0f;

    half8 qf[2][2];
    {
        const _Float16* qrow =
            qt + ((((size_t)(bh)) << 10) + p0 + w * 32 + l15) * 64;
#pragma unroll
        for (int iff = 0; iff < 2; ++iff)
#pragma unroll
            for (int ks = 0; ks < 2; ++ks)
                qf[iff][ks] = *(const half8*)(qrow + iff * 16 * 64 + ks * 32 + quad * 8);
    }

    const _Float16* kbase = ktp + ((size_t)bh << 16);
    const _Float16* vbase = vbb + (((size_t)(b * 512 + h * 64)) << 10);

    f32x4 oacc[4][2];
#pragma unroll
    for (int mf = 0; mf < 4; ++mf)
#pragma unroll
        for (int iff = 0; iff < 2; ++iff) oacc[mf][iff] = Z4;
    f32x4 racc[2] = {Z4, Z4};

    const int kchunk = (lane & 7) ^ (lane >> 3);
    for (int kt = 0; kt < 8; ++kt) {
        const int pk = kt * 128;
        __syncthreads();
        const _Float16* kg = kbase + (size_t)pk * 64;
#pragma unroll
        for (int i = 0; i < 4; ++i) {
            const int t = i * 4 + w;
            gload16(kg + (t * 8 + (lane >> 3)) * 64 + kchunk * 8, &Ks[t * 512]);
        }
#pragma unroll
        for (int i = 0; i < 4; ++i) {
            const int t = i * 4 + w;
            const int vd = t * 4 + (lane >> 4);
            gload16(vbase + ((size_t)vd << 10) + pk + (((lane & 15) ^ (vd & 15)) << 3),
                    &Vs[t * 512]);
        }
        __syncthreads();

#pragma unroll
        for (int g = 0; g < 2; ++g) {
            f32x4 s[4][2];
#pragma unroll
            for (int jf2 = 0; jf2 < 4; ++jf2) {
                const int jr = (g * 4 + jf2) * 16 + l15;
                const half8 ka0 = *(const half8*)&Ks[jr * 64 + ((quad ^ (l15 & 7)) << 3)];
                const half8 ka1 = *(const half8*)&Ks[jr * 64 + (((4 + quad) ^ (l15 & 7)) << 3)];
#pragma unroll
                for (int iff = 0; iff < 2; ++iff) {
                    s[jf2][iff] = MFMA16(ka0, qf[iff][0], Z4);
                    s[jf2][iff] = MFMA16(ka1, qf[iff][1], s[jf2][iff]);
                }
            }
#pragma unroll
            for (int jf2 = 0; jf2 < 4; ++jf2) {
#pragma unroll
                for (int iff = 0; iff < 2; ++iff) {
                    half4 pv4;
#pragma unroll
                    for (int r = 0; r < 4; ++r)
                        pv4[r] = (_Float16)__expf(s[jf2][iff][r] - 8.0f);
                    const int i = w * 32 + iff * 16 + l15;
                    const int c = ((g * 4 + jf2) << 1) + (quad >> 1);
                    *(half4*)&Pb[i * 128 + ((c ^ l15) << 3) + ((quad & 1) << 2)] = pv4;
                }
            }
        }
#pragma unroll
        for (int kc = 0; kc < 4; ++kc) {
            half8 bv[2];
#pragma unroll
            for (int iff = 0; iff < 2; ++iff) {
                const int i = w * 32 + iff * 16 + l15;
                bv[iff] = *(const half8*)&Pb[i * 128 + (((kc * 4 + quad) ^ l15) << 3)];
                racc[iff] = MFMA16(ones, bv[iff], racc[iff]);
            }
#pragma unroll
            for (int mf = 0; mf < 4; ++mf) {
                const int vr = mf * 16 + l15;
                const half8 va = *(const half8*)&Vs[vr * 128 + (((kc * 4 + quad) ^ l15) << 3)];
#pragma unroll
                for (int iff = 0; iff < 2; ++iff)
                    oacc[mf][iff] = MFMA16(va, bv[iff], oacc[mf][iff]);
            }
        }
    }

    float rinv[2];
#pragma unroll
    for (int iff = 0; iff < 2; ++iff) rinv[iff] = 1.f / racc[iff][0];

    __syncthreads();
    _Float16* scr = Pb;  // [128 rows][72 halves]
#pragma unroll
    for (int mf = 0; mf < 4; ++mf) {
#pragma unroll
        for (int iff = 0; iff < 2; ++iff) {
            half4 o4;
#pragma unroll
            for (int r = 0; r < 4; ++r)
                o4[r] = (_Float16)gelu_f(oacc[mf][iff][r] * rinv[iff]);
            const int i = w * 32 + iff * 16 + l15;
            *(half4*)&scr[i * 72 + mf * 16 + quad * 4] = o4;
        }
    }
    __syncthreads();
    _Float16* go = gout + ((size_t)(b * NPIX + p0)) * INNER + h * 64;
#pragma unroll
    for (int it = 0; it < 4; ++it) {
        const int e = tid + it * 256;
        const int p = e >> 3, dg = e & 7;
        *(half8*)(go + (size_t)p * INNER + dg * 8) = *(const half8*)&scr[p * 72 + dg * 8];
    }
}

// ---------------------------------------------------------------------------
// Workspace (f16 units, ~43.5 MB):
//   xtp 2.37M | Aq 128K | Akv 2.25M | Aout 128K | qt 4M | vb 4M | ktp 4M | gout 4M
// ---------------------------------------------------------------------------
extern "C" void kernel_launch(void* const* d_in, const int* in_sizes, int n_in,
                              void* d_out, int out_size, void* d_ws, size_t ws_size,
                              hipStream_t stream)
{
    const float* x    = (const float*)d_in[0];
    const float* Wq   = (const float*)d_in[1];
    const float* Wkv  = (const float*)d_in[2];
    const float* Wout = (const float*)d_in[3];
    const float* bout = (const float*)d_in[4];
    float* out = (float*)d_out;

    _Float16* xtp  = (_Float16*)d_ws;
    _Float16* Aq   = xtp  + (size_t)BATCH * PPIX * DIM;
    _Float16* Akv  = Aq   + (size_t)INNER * DIM;
    _Float16* Aout = Akv  + (size_t)KVCH * 2304;
    _Float16* qt   = Aout + (size_t)DIM * INNER;
    _Float16* vb   = qt   + (size_t)BATCH * NPIX * INNER;
    _Float16* ktp  = vb   + (size_t)BATCH * NPIX * INNER;
    _Float16* gout = ktp  + (size_t)BATCH * NPIX * INNER;

    // zero the padded-x halo (interior overwritten by transpose_x)
    (void)hipMemsetAsync(xtp, 0, (size_t)BATCH * PPIX * DIM * sizeof(_Float16), stream);

    prep_w_kernel<<<10240, 256, 0, stream>>>(Wq, Wkv, Wout, Aq, Akv, Aout);
    transpose_x_kernel<<<dim3(16, 4, BATCH), 256, 0, stream>>>(x, xtp);
    qkv_gemm_kernel<<<dim3(16, 12, BATCH), 256, 0, stream>>>(Akv, Aq, xtp, qt, ktp, vb);
    attn_kernel<<<dim3(8, 64), 256, 0, stream>>>(qt, ktp, vb, gout);
    out_gemm_kernel<DIM, 512, 512>
        <<<dim3(16, 2, BATCH), 256, 0, stream>>>(Aout, gout, out, bout);
}

// Round 9
// 176.257 us; speedup vs baseline: 1.0902x; 1.0794x over previous
//
#include <hip/hip_runtime.h>
#include <math.h>

// Attention_5471788335537 on gfx950: b=8, dim=256, 32x32, heads=8, dhead=64.
// Round 9: (1) qkv GEMM moves to mfma_f32_32x32x16_f16, tile 128x128, 2x2
// waves — 2x FLOP per LDS fragment byte (r8 model: LDS bank time was the
// pipe, predicted 27% MfmaUtil vs 28% measured); (2) memset+prep_w+
// transpose_x fused into one prep kernel (dispatch gaps ~10us each;
// 6 dispatches -> 4).
#define BATCH 8
#define DIM   256
#define NPIX  1024
#define DHEAD 64
#define INNER 512
#define KVCH  1024
#define PPIX  1156   // 34*34 padded pixels

typedef _Float16 half8 __attribute__((ext_vector_type(8)));
typedef _Float16 half4 __attribute__((ext_vector_type(4)));
typedef float    f32x4 __attribute__((ext_vector_type(4)));
typedef float    f32x16 __attribute__((ext_vector_type(16)));
#define MFMA16(a, b, c) __builtin_amdgcn_mfma_f32_16x16x32_f16(a, b, c, 0, 0, 0)
#define MFMA32(a, b, c) __builtin_amdgcn_mfma_f32_32x32x16_f16(a, b, c, 0, 0, 0)

static __device__ __forceinline__ float gelu_f(float v) {
    return 0.5f * v * (1.0f + erff(v * 0.70710678118654752440f));
}

static __device__ __forceinline__ void gload16(const _Float16* g, _Float16* l) {
    __builtin_amdgcn_global_load_lds(
        (const __attribute__((address_space(1))) unsigned int*)g,
        (__attribute__((address_space(3))) unsigned int*)l, 16, 0, 0);
}

// ---------------------------------------------------------------------------
// Fused prep: [0,512) transpose x -> padded xtp interior; [512,10752) weights
// -> f16 (Wkv reordered [oc][ic][9] -> [oc][s*256+ic]); [10752,...) zero the
// xtp halo (132 halo pixels x 256 ch x 8 b). One dispatch replaces three.
// ---------------------------------------------------------------------------
__global__ __launch_bounds__(256) void prep_kernel(
    const float* __restrict__ Wq, const float* __restrict__ Wkv,
    const float* __restrict__ Wout, const float* __restrict__ x,
    _Float16* __restrict__ Aq, _Float16* __restrict__ Akv,
    _Float16* __restrict__ Aout, _Float16* __restrict__ xtp)
{
    const int bid = blockIdx.x, tid = threadIdx.x;
    if (bid < 512) {
        __shared__ float ts[64][65];
        const int pt = (bid & 15) * 64, ic0 = ((bid >> 4) & 3) * 64, b = bid >> 6;
        const float* xb = x + (((size_t)(b * DIM + ic0)) << 10) + pt;
#pragma unroll
        for (int e = tid; e < 4096; e += 256) {
            int i = e >> 6, p = e & 63;
            ts[i][p] = xb[((size_t)i << 10) + p];
        }
        __syncthreads();
#pragma unroll
        for (int e = tid; e < 512; e += 256) {
            int p = e >> 3, ig = e & 7;
            int gp = pt + p, y = gp >> 5, xc = gp & 31;
            half8 v;
#pragma unroll
            for (int u = 0; u < 8; ++u) v[u] = (_Float16)ts[ig * 8 + u][p];
            *(half8*)&xtp[((size_t)b * PPIX + (y + 1) * 34 + xc + 1) * 256 + ic0 + ig * 8] = v;
        }
    } else if (bid < 10752) {
        const int e = (bid - 512) * 256 + tid;
        if (e < 131072) Aq[e] = (_Float16)Wq[e];
        const int e2 = e - 131072;
        if (e2 >= 0 && e2 < 2359296) {
            int oc = e2 / 2304, r = e2 - oc * 2304;
            int s = r >> 8, ic = r & 255;
            Akv[e2] = (_Float16)Wkv[oc * 2304 + ic * 9 + s];
        }
        const int e3 = e - 131072 - 2359296;
        if (e3 >= 0 && e3 < 131072) Aout[e3] = (_Float16)Wout[e3];
    } else {
        const int he = (bid - 10752) * 256 + tid;
        if (he < 270336) {
            int b = he / 33792;            // 132*256 per batch
            int r = he - b * 33792;
            int hp = r >> 8, ic = r & 255;
            int row, col;
            if (hp < 34)      { row = 0;  col = hp; }
            else if (hp < 68) { row = 33; col = hp - 34; }
            else { int k2 = hp - 68; row = 1 + (k2 >> 1); col = (k2 & 1) * 33; }
            xtp[((size_t)b * PPIX + row * 34 + col) * 256 + ic] = (_Float16)0.f;
        }
    }
}

// ---------------------------------------------------------------------------
// Fused q + kv implicit GEMM, 32x32x16 MFMA, tile 128M x 128N, waves 2x2.
// grid (8 pixtiles, 12, 8). mt<8: A=Akv (36 kts, shift via wave-uniform
// padded offset); mt<4 -> K headwise, mt 4..7 -> V channel-major.
// mt>=8: A=Aq (4 kts, center shift), q*0.125 -> qt headwise.
// XOR-chunk staging swizzle (key=row&7); frag reads conflict-free.
// A/B frag: m(n)=lane&31, k=(lane>>5)*8+j. C/D: col=lane&31,
// row=(reg&3)+8*(reg>>2)+4*(lane>>5)  [m74/m101-verified].
// ---------------------------------------------------------------------------
__global__ __launch_bounds__(256) void qkv_gemm_kernel(
    const _Float16* __restrict__ Akv, const _Float16* __restrict__ Aq,
    const _Float16* __restrict__ xtp, _Float16* __restrict__ qt,
    _Float16* __restrict__ ktp, _Float16* __restrict__ vb)
{
    __shared__ _Float16 As[128 * 64];   // 16 KB
    __shared__ _Float16 Bs[128 * 64];   // 16 KB
    const int nt = blockIdx.x, mt = blockIdx.y, b = blockIdx.z;
    const bool QBLK = (mt >= 8);
    const int tid = threadIdx.x;
    const int w = tid >> 6, lane = tid & 63;
    const int l31 = lane & 31, kh = lane >> 5;
    const int m0 = (QBLK ? mt - 8 : mt) * 128, p0 = nt * 128;
    const int wm = (w >> 1) * 64, wn = (w & 1) * 64;

    const int srow = lane >> 3;
    const int scol = ((lane & 7) ^ srow) * 8;

    const _Float16* abase = QBLK ? Aq : Akv;
    const int astride = QBLK ? 256 : 2304;
    const int ktend = QBLK ? 4 : 36;

    const _Float16* agp[4];
    const _Float16* bgp[4];
#pragma unroll
    for (int c = 0; c < 4; ++c) {
        int row = (w * 4 + c) * 8 + srow;
        agp[c] = abase + (size_t)(m0 + row) * astride + scol;
        int p = p0 + row, py = p >> 5, px = p & 31;
        bgp[c] = xtp + ((size_t)b * PPIX + (py + 1) * 34 + px + 1) * 256 + scol;
    }

    f32x16 acc[2][2];
#pragma unroll
    for (int mf = 0; mf < 2; ++mf)
#pragma unroll
        for (int nf = 0; nf < 2; ++nf)
#pragma unroll
            for (int r = 0; r < 16; ++r) acc[mf][nf][r] = 0.f;

    for (int kt = 0; kt < ktend; ++kt) {
        __syncthreads();
        const int s = QBLK ? 4 : (kt >> 2);
        const int doff = (s / 3 - 1) * 34 + (s - (s / 3) * 3) - 1;   // dy*34+dx
        const int boff = doff * 256 + (kt & 3) * 64;                 // wave-uniform
#pragma unroll
        for (int c = 0; c < 4; ++c)
            gload16(agp[c] + kt * 64, &As[(w * 4 + c) * 512]);
#pragma unroll
        for (int c = 0; c < 4; ++c)
            gload16(bgp[c] + boff, &Bs[(w * 4 + c) * 512]);
        __syncthreads();
#pragma unroll
        for (int kc = 0; kc < 4; ++kc) {
            const int cx = ((((kc << 1) | kh) ^ (l31 & 7)) << 3);
            half8 af[2], bf[2];
#pragma unroll
            for (int mf = 0; mf < 2; ++mf)
                af[mf] = *(const half8*)&As[(wm + mf * 32 + l31) * 64 + cx];
#pragma unroll
            for (int nf = 0; nf < 2; ++nf)
                bf[nf] = *(const half8*)&Bs[(wn + nf * 32 + l31) * 64 + cx];
#pragma unroll
            for (int mf = 0; mf < 2; ++mf)
#pragma unroll
                for (int nf = 0; nf < 2; ++nf)
                    acc[mf][nf] = MFMA32(af[mf], bf[nf], acc[mf][nf]);
        }
    }

#pragma unroll
    for (int mf = 0; mf < 2; ++mf) {
        const int mbase = m0 + wm + mf * 32;   // multiple of 32
        if (!QBLK && mbase >= 512) {
            // V: f16 channel-major [(b*512 + m-512)<<10 + pix]
#pragma unroll
            for (int nf = 0; nf < 2; ++nf) {
                const int pix = p0 + wn + nf * 32 + l31;
#pragma unroll
                for (int reg = 0; reg < 16; ++reg) {
                    const int mv = mbase - 512 + (reg & 3) + 8 * (reg >> 2) + 4 * kh;
                    vb[(((size_t)(b * 512 + mv)) << 10) + pix] =
                        (_Float16)acc[mf][nf][reg];
                }
            }
        } else {
            // headwise: [(b*8+h)<<10 + pix][64], d contiguous in groups of 4
            const int h = mbase >> 6;
            const int dbase = (mbase & 63) + kh * 4;
            _Float16* dst = QBLK ? qt : ktp;
#pragma unroll
            for (int nf = 0; nf < 2; ++nf) {
                const int pix = p0 + wn + nf * 32 + l31;
#pragma unroll
                for (int g = 0; g < 4; ++g) {
                    half4 v4;
#pragma unroll
                    for (int r = 0; r < 4; ++r) {
                        float vv = acc[mf][nf][g * 4 + r];
                        if (QBLK) vv *= 0.125f;
                        v4[r] = (_Float16)vv;
                    }
                    *(half4*)&dst[((((size_t)(b * 8 + h)) << 10) + pix) * 64 + dbase + g * 8] = v4;
                }
            }
        }
    }
}

// ---------------------------------------------------------------------------
// Output projection GEMM (r8 version, 16x16x32, tile 128M x 64N, 256 blocks).
// ---------------------------------------------------------------------------
template<int M, int K, int KROW>
__global__ __launch_bounds__(256) void out_gemm_kernel(
    const _Float16* __restrict__ A, const _Float16* __restrict__ act,
    float* __restrict__ Cout, const float* __restrict__ bias)
{
    __shared__ _Float16 As[128 * 64];
    __shared__ _Float16 Bs[64 * 64];
    const int nt = blockIdx.x, mt = blockIdx.y, b = blockIdx.z;
    const int tid = threadIdx.x;
    const int w = tid >> 6, lane = tid & 63;
    const int quad = lane >> 4, l15 = lane & 15;
    const int m0 = mt * 128, p0 = nt * 64;
    const int wm = w * 32;
    const f32x4 Z4 = {0.f, 0.f, 0.f, 0.f};

    const int srow = lane >> 3;
    const int scol = ((lane & 7) ^ srow) * 8;

    const _Float16* agp[4];
#pragma unroll
    for (int c = 0; c < 4; ++c) {
        int row = (w * 4 + c) * 8 + srow;
        agp[c] = A + (size_t)(m0 + row) * K + scol;
    }
    const _Float16* bgp[2];
#pragma unroll
    for (int c = 0; c < 2; ++c) {
        int row = (w * 2 + c) * 8 + srow;
        bgp[c] = act + (size_t)(b * NPIX + p0 + row) * KROW + scol;
    }

    f32x4 acc[2][4];
#pragma unroll
    for (int mi = 0; mi < 2; ++mi)
#pragma unroll
        for (int ni = 0; ni < 4; ++ni) acc[mi][ni] = Z4;

    for (int kt = 0; kt < K / 64; ++kt) {
        __syncthreads();
#pragma unroll
        for (int c = 0; c < 4; ++c)
            gload16(agp[c] + kt * 64, &As[(w * 4 + c) * 512]);
#pragma unroll
        for (int c = 0; c < 2; ++c)
            gload16(bgp[c] + kt * 64, &Bs[(w * 2 + c) * 512]);
        __syncthreads();
#pragma unroll
        for (int ks = 0; ks < 2; ++ks) {
            half8 av[2], bv[4];
#pragma unroll
            for (int mi = 0; mi < 2; ++mi) {
                const int r = wm + mi * 16 + l15;
                av[mi] = *(const half8*)&As[r * 64 + (((ks * 4 + quad) ^ (l15 & 7)) << 3)];
            }
#pragma unroll
            for (int ni = 0; ni < 4; ++ni) {
                const int r = ni * 16 + l15;
                bv[ni] = *(const half8*)&Bs[r * 64 + (((ks * 4 + quad) ^ (l15 & 7)) << 3)];
            }
#pragma unroll
            for (int mi = 0; mi < 2; ++mi)
#pragma unroll
                for (int ni = 0; ni < 4; ++ni)
                    acc[mi][ni] = MFMA16(av[mi], bv[ni], acc[mi][ni]);
        }
    }

#pragma unroll
    for (int mi = 0; mi < 2; ++mi) {
#pragma unroll
        for (int r = 0; r < 4; ++r) {
            const int m = m0 + wm + mi * 16 + quad * 4 + r;
            const float bv = bias[m];
#pragma unroll
            for (int ni = 0; ni < 4; ++ni) {
                const int pix = p0 + ni * 16 + l15;
                Cout[(((size_t)(b * M + m)) << 10) + pix] = acc[mi][ni][r] + bv;
            }
        }
    }
}

// ---------------------------------------------------------------------------
// Attention (round-6 structure, unchanged: native exp, ones-MFMA row sums,
// S^T layout, xor-swizzled staging, wave-private P).
// ---------------------------------------------------------------------------
__global__ __launch_bounds__(256) void attn_kernel(
    const _Float16* __restrict__ qt,   // [(b*8+h)<<10 + pix]*64 + d, pre-scaled
    const _Float16* __restrict__ ktp,  // (bh<<16) + pix*64 + d
    const _Float16* __restrict__ vbb,  // [(b*512 + h*64 + d)<<10] + pix
    _Float16* __restrict__ gout)       // [b*1024+pix][512]
{
    __shared__ _Float16 Ks[128 * 64];
    __shared__ _Float16 Vs[64 * 128];
    __shared__ _Float16 Pb[128 * 128];
    const int qtile = blockIdx.x, bh = blockIdx.y;
    const int b = bh >> 3, h = bh & 7;
    const int p0 = qtile * 128;
    const int tid = threadIdx.x;
    const int w = tid >> 6, lane = tid & 63;
    const int quad = lane >> 4, l15 = lane & 15;
    const f32x4 Z4 = {0.f, 0.f, 0.f, 0.f};

    half8 ones;
#pragma unroll
    for (int u = 0; u < 8; ++u) ones[u] = (_Float16)1.0f;

    half8 qf[2][2];
    {
        const _Float16* qrow =
            qt + ((((size_t)(bh)) << 10) + p0 + w * 32 + l15) * 64;
#pragma unroll
        for (int iff = 0; iff < 2; ++iff)
#pragma unroll
            for (int ks = 0; ks < 2; ++ks)
                qf[iff][ks] = *(const half8*)(qrow + iff * 16 * 64 + ks * 32 + quad * 8);
    }

    const _Float16* kbase = ktp + ((size_t)bh << 16);
    const _Float16* vbase = vbb + (((size_t)(b * 512 + h * 64)) << 10);

    f32x4 oacc[4][2];
#pragma unroll
    for (int mf = 0; mf < 4; ++mf)
#pragma unroll
        for (int iff = 0; iff < 2; ++iff) oacc[mf][iff] = Z4;
    f32x4 racc[2] = {Z4, Z4};

    const int kchunk = (lane & 7) ^ (lane >> 3);
    for (int kt = 0; kt < 8; ++kt) {
        const int pk = kt * 128;
        __syncthreads();
        const _Float16* kg = kbase + (size_t)pk * 64;
#pragma unroll
        for (int i = 0; i < 4; ++i) {
            const int t = i * 4 + w;
            gload16(kg + (t * 8 + (lane >> 3)) * 64 + kchunk * 8, &Ks[t * 512]);
        }
#pragma unroll
        for (int i = 0; i < 4; ++i) {
            const int t = i * 4 + w;
            const int vd = t * 4 + (lane >> 4);
            gload16(vbase + ((size_t)vd << 10) + pk + (((lane & 15) ^ (vd & 15)) << 3),
                    &Vs[t * 512]);
        }
        __syncthreads();

#pragma unroll
        for (int g = 0; g < 2; ++g) {
            f32x4 s[4][2];
#pragma unroll
            for (int jf2 = 0; jf2 < 4; ++jf2) {
                const int jr = (g * 4 + jf2) * 16 + l15;
                const half8 ka0 = *(const half8*)&Ks[jr * 64 + ((quad ^ (l15 & 7)) << 3)];
                const half8 ka1 = *(const half8*)&Ks[jr * 64 + (((4 + quad) ^ (l15 & 7)) << 3)];
#pragma unroll
                for (int iff = 0; iff < 2; ++iff) {
                    s[jf2][iff] = MFMA16(ka0, qf[iff][0], Z4);
                    s[jf2][iff] = MFMA16(ka1, qf[iff][1], s[jf2][iff]);
                }
            }
#pragma unroll
            for (int jf2 = 0; jf2 < 4; ++jf2) {
#pragma unroll
                for (int iff = 0; iff < 2; ++iff) {
                    half4 pv4;
#pragma unroll
                    for (int r = 0; r < 4; ++r)
                        pv4[r] = (_Float16)__expf(s[jf2][iff][r] - 8.0f);
                    const int i = w * 32 + iff * 16 + l15;
                    const int c = ((g * 4 + jf2) << 1) + (quad >> 1);
                    *(half4*)&Pb[i * 128 + ((c ^ l15) << 3) + ((quad & 1) << 2)] = pv4;
                }
            }
        }
#pragma unroll
        for (int kc = 0; kc < 4; ++kc) {
            half8 bv[2];
#pragma unroll
            for (int iff = 0; iff < 2; ++iff) {
                const int i = w * 32 + iff * 16 + l15;
                bv[iff] = *(const half8*)&Pb[i * 128 + (((kc * 4 + quad) ^ l15) << 3)];
                racc[iff] = MFMA16(ones, bv[iff], racc[iff]);
            }
#pragma unroll
            for (int mf = 0; mf < 4; ++mf) {
                const int vr = mf * 16 + l15;
                const half8 va = *(const half8*)&Vs[vr * 128 + (((kc * 4 + quad) ^ l15) << 3)];
#pragma unroll
                for (int iff = 0; iff < 2; ++iff)
                    oacc[mf][iff] = MFMA16(va, bv[iff], oacc[mf][iff]);
            }
        }
    }

    float rinv[2];
#pragma unroll
    for (int iff = 0; iff < 2; ++iff) rinv[iff] = 1.f / racc[iff][0];

    __syncthreads();
    _Float16* scr = Pb;  // [128 rows][72 halves]
#pragma unroll
    for (int mf = 0; mf < 4; ++mf) {
#pragma unroll
        for (int iff = 0; iff < 2; ++iff) {
            half4 o4;
#pragma unroll
            for (int r = 0; r < 4; ++r)
                o4[r] = (_Float16)gelu_f(oacc[mf][iff][r] * rinv[iff]);
            const int i = w * 32 + iff * 16 + l15;
            *(half4*)&scr[i * 72 + mf * 16 + quad * 4] = o4;
        }
    }
    __syncthreads();
    _Float16* go = gout + ((size_t)(b * NPIX + p0)) * INNER + h * 64;
#pragma unroll
    for (int it = 0; it < 4; ++it) {
        const int e = tid + it * 256;
        const int p = e >> 3, dg = e & 7;
        *(half8*)(go + (size_t)p * INNER + dg * 8) = *(const half8*)&scr[p * 72 + dg * 8];
    }
}

// ---------------------------------------------------------------------------
// Workspace (f16 units, ~43.4 MB):
//   xtp 2.37M | Aq 128K | Akv 2.25M | Aout 128K | qt 4M | vb 4M | ktp 4M | gout 4M
// 4 dispatches: prep, qkv, attn, out.
// ---------------------------------------------------------------------------
extern "C" void kernel_launch(void* const* d_in, const int* in_sizes, int n_in,
                              void* d_out, int out_size, void* d_ws, size_t ws_size,
                              hipStream_t stream)
{
    const float* x    = (const float*)d_in[0];
    const float* Wq   = (const float*)d_in[1];
    const float* Wkv  = (const float*)d_in[2];
    const float* Wout = (const float*)d_in[3];
    const float* bout = (const float*)d_in[4];
    float* out = (float*)d_out;

    _Float16* xtp  = (_Float16*)d_ws;
    _Float16* Aq   = xtp  + (size_t)BATCH * PPIX * DIM;
    _Float16* Akv  = Aq   + (size_t)INNER * DIM;
    _Float16* Aout = Akv  + (size_t)KVCH * 2304;
    _Float16* qt   = Aout + (size_t)DIM * INNER;
    _Float16* vb   = qt   + (size_t)BATCH * NPIX * INNER;
    _Float16* ktp  = vb   + (size_t)BATCH * NPIX * INNER;
    _Float16* gout = ktp  + (size_t)BATCH * NPIX * INNER;

    prep_kernel<<<11808, 256, 0, stream>>>(Wq, Wkv, Wout, x, Aq, Akv, Aout, xtp);
    qkv_gemm_kernel<<<dim3(8, 12, BATCH), 256, 0, stream>>>(Akv, Aq, xtp, qt, ktp, vb);
    attn_kernel<<<dim3(8, 64), 256, 0, stream>>>(qt, ktp, vb, gout);
    out_gemm_kernel<DIM, 512, 512>
        <<<dim3(16, 2, BATCH), 256, 0, stream>>>(Aout, gout, out, bout);
}